// Round 5
// baseline (364.181 us; speedup 1.0000x reference)
//
#include <hip/hip_runtime.h>
#include <stdint.h>

#define BATCH 4
#define NA 6
#define NC 80
#define HW (128*128)            // 16384
#define NPB (NA*HW)             // 98304 anchors per batch
#define KPRE 4095
#define POSTK 300
#define NEGV (-(1<<30))
#define NCHUNK (NPB/256)        // 384 chunks of 256 per batch
#define R1 1024                 // rows with precomputed NMS masks (fast path)

// ---------------- workspace layout (bytes) ----------------
#define OFF_BOXES    0                         // float4 [B][NPB]          6291456
#define OFF_MS       6291456                   // int [B][NPB] s<<7|lab    1572864
#define OFF_BCNT     7864320                   // int [B][128][384]         786432
#define OFF_TOT      8650752                   // int [B][128]                2048
#define OFF_TOPV     8652800                   // int [B][4096]              65536
#define OFF_LABK     8718336                   // int [B][4096]              65536
#define OFF_BOXK     8783872                   // float4 [B][4096]          262144
#define OFF_MASK     9046016                   // u64 [B][R1][64]          2097152
#define OFF_DIAG     11143168                  // u64 [B][R1]                32768
// total ~11.2 MB

__device__ __forceinline__ float4 dpp_decode_box(int dxi, int dyi, int dwi, int dhi,
                                                 float a0, float a1, float a2, float a3,
                                                 const int* __restrict__ exp_table, float esc) {
#pragma clang fp contract(off)
    float aw  = a2 - a0;
    float ah  = a3 - a1;
    float acx = (a0 + a2) * 0.5f;
    float acy = (a1 + a3) * 0.5f;
    float dx  = (float)dxi * 0.0625f;     // 1/2^INPUT_SHIFT
    float dy  = (float)dyi * 0.0625f;
    int e2 = dwi < -128 ? -128 : (dwi > 127 ? 127 : dwi);
    int e3 = dhi < -128 ? -128 : (dhi > 127 ? 127 : dhi);
    float ew = (float)exp_table[e2 + 128] * esc;
    float eh = (float)exp_table[e3 + 128] * esc;
    float pcx = acx + dx * aw;
    float pcy = acy + dy * ah;
    float pw = aw * ew;
    float ph = ah * eh;
    float x0 = pcx - pw * 0.5f;
    float y0 = pcy - ph * 0.5f;
    float x1 = pcx + pw * 0.5f;
    float y1 = pcy + ph * 0.5f;
    x0 = fminf(fmaxf(x0, 0.f), 1024.f);
    y0 = fminf(fmaxf(y0, 0.f), 1024.f);
    x1 = fminf(fmaxf(x1, 0.f), 1024.f);
    y1 = fminf(fmaxf(y1, 0.f), 1024.f);
    return make_float4(x0, y0, x1, y1);
}

// exact reference IoU-suppression test (fp contract off, IEEE divide)
__device__ __forceinline__ bool dpp_sup_test(float4 p, float pa, int pl_, float4 c, int cl_) {
#pragma clang fp contract(off)
    float cw = fmaxf(c.z - c.x, 0.f), ch = fmaxf(c.w - c.y, 0.f);
    float ca = cw * ch;
    float lx = fmaxf(p.x, c.x), ly = fmaxf(p.y, c.y);
    float rx = fminf(p.z, c.z), ry = fminf(p.w, c.w);
    float wx = fmaxf(rx - lx, 0.f), wy = fmaxf(ry - ly, 0.f);
    float inter = wx * wy;
    float uni = fmaxf((pa + ca) - inter, 1e-6f);
    float iou = inter / uni;
    return (iou > 0.5f) && (cl_ == pl_);
}

// grid (16, NA, BATCH), 256 threads; each thread decodes 4 anchors via int4 (16B/lane) loads.
// R3-proven structure; labels packed into ms as score<<7|label.
__global__ __launch_bounds__(256) void dpp_decode_kernel(
        const int* __restrict__ data, const float* __restrict__ anchor,
        const int* __restrict__ exp_table, const int* __restrict__ exp_shift_p,
        int* __restrict__ ms, float4* __restrict__ boxes, int* __restrict__ blockcnt) {
    int b = blockIdx.z, a = blockIdx.y, tid = threadIdx.x;
    int idx = blockIdx.x * 256 + tid;                    // int4 index in [0, 4096)
    const int4* dptr = (const int4*)(data + (size_t)(b * NA + a) * 84 * HW);

    int4 d0 = dptr[idx];
    int4 d1 = dptr[4096 + idx];
    int4 d2 = dptr[2 * 4096 + idx];
    int4 d3 = dptr[3 * 4096 + idx];

    int4 m = dptr[4 * 4096 + idx];
    int4 lab = make_int4(0, 0, 0, 0);
#pragma unroll 4
    for (int c = 1; c < NC; c++) {
        int4 v = dptr[(4 + c) * 4096 + idx];
        if (v.x > m.x) { m.x = v.x; lab.x = c; }         // strict > : first-argmax
        if (v.y > m.y) { m.y = v.y; lab.y = c; }
        if (v.z > m.z) { m.z = v.z; lab.z = c; }
        if (v.w > m.w) { m.w = v.w; lab.w = c; }
    }

    const float4* aptr = (const float4*)(anchor + (size_t)a * 4 * HW);
    float4 ax0 = aptr[idx];
    float4 ay0 = aptr[4096 + idx];
    float4 ax1 = aptr[2 * 4096 + idx];
    float4 ay1 = aptr[3 * 4096 + idx];

    int eshift = exp_shift_p[0];
    float esc = 1.0f / (float)(1 << eshift);

    float4 box0 = dpp_decode_box(d0.x, d1.x, d2.x, d3.x, ax0.x, ay0.x, ax1.x, ay1.x, exp_table, esc);
    float4 box1 = dpp_decode_box(d0.y, d1.y, d2.y, d3.y, ax0.y, ay0.y, ax1.y, ay1.y, exp_table, esc);
    float4 box2 = dpp_decode_box(d0.z, d1.z, d2.z, d3.z, ax0.z, ay0.z, ax1.z, ay1.z, exp_table, esc);
    float4 box3 = dpp_decode_box(d0.w, d1.w, d2.w, d3.w, ax0.w, ay0.w, ax1.w, ay1.w, exp_table, esc);

    int p0 = (m.x >= 1) ? ((m.x << 7) | lab.x) : NEGV;   // THR_INT = 1
    int p1 = (m.y >= 1) ? ((m.y << 7) | lab.y) : NEGV;
    int p2 = (m.z >= 1) ? ((m.z << 7) | lab.z) : NEGV;
    int p3 = (m.w >= 1) ? ((m.w << 7) | lab.w) : NEGV;

    size_t nb = (size_t)b * NPB + (size_t)a * HW;        // multiple of 4
    ((int4*)ms)[(nb >> 2) + idx] = make_int4(p0, p1, p2, p3);
    boxes[nb + 4 * (size_t)idx]     = box0;
    boxes[nb + 4 * (size_t)idx + 1] = box1;
    boxes[nb + 4 * (size_t)idx + 2] = box2;
    boxes[nb + 4 * (size_t)idx + 3] = box3;

    // per-256-anchor-chunk score histogram (stable counting-sort input)
    __shared__ int hist[512];                            // [4 quarters][128 scores]
    hist[tid] = 0;
    hist[tid + 256] = 0;
    __syncthreads();
    int q = tid >> 6;                                    // 64 threads * 4 anchors = 256-chunk
    if (m.x >= 1) atomicAdd(&hist[q * 128 + m.x], 1);
    if (m.y >= 1) atomicAdd(&hist[q * 128 + m.y], 1);
    if (m.z >= 1) atomicAdd(&hist[q * 128 + m.z], 1);
    if (m.w >= 1) atomicAdd(&hist[q * 128 + m.w], 1);
    __syncthreads();
#pragma unroll
    for (int k = 0; k < 2; k++) {
        int lin = tid + (k << 8);
        int q2 = lin >> 7, v = lin & 127;
        int chunk = a * 64 + blockIdx.x * 4 + q2;        // global 256-chunk id in [0,384)
        blockcnt[((b << 7) + v) * NCHUNK + chunk] = hist[q2 * 128 + v];
    }
}

// grid (128, BATCH), 384 threads: in-place exclusive scan of bcnt[b][v][0..384); total -> tot[b][v]
// (coalesced loads; shuffle scan). Also initializes this block's 32 slots of topv/labk/boxk.
__global__ __launch_bounds__(384) void dpp_scan_kernel(int* __restrict__ bcnt,
                                                       int* __restrict__ tot,
                                                       int* __restrict__ topv,
                                                       int* __restrict__ labk,
                                                       float4* __restrict__ boxk) {
    int v = blockIdx.x, b = blockIdx.y, t = threadIdx.x;
    if (t < 32) {
        int slot = (b << 12) + (v << 5) + t;
        topv[slot] = NEGV;
        labk[slot] = 0;
        boxk[slot] = make_float4(0.f, 0.f, 0.f, 0.f);
    }
    int* bc = bcnt + ((b << 7) + v) * NCHUNK;
    int x = bc[t];
    int lane = t & 63, w = t >> 6;                       // 6 waves
    int s = x;
#pragma unroll
    for (int d = 1; d < 64; d <<= 1) {
        int y = __shfl_up(s, d);
        if (lane >= d) s += y;
    }
    __shared__ int wsum[6];
    if (lane == 63) wsum[w] = s;
    __syncthreads();
    int off = 0;
    for (int i = 0; i < w; i++) off += wsum[i];
    int incl = s + off;
    bc[t] = incl - x;                                    // exclusive
    if (t == NCHUNK - 1) tot[(b << 7) + v] = incl;
}

// grid (NCHUNK, BATCH), 256 threads: fused cutoff (per-block redundant, from tot) + exact
// stable rank -> scatter into sorted topv/labk/boxk (box gathered from decode's output).
__global__ __launch_bounds__(256) void dpp_place_kernel(
        const int* __restrict__ ms, const float4* __restrict__ boxes,
        const int* __restrict__ blockoff, const int* __restrict__ tot,
        int* __restrict__ topv, int* __restrict__ labk, float4* __restrict__ boxk) {
    int chunk = blockIdx.x, b = blockIdx.y, tid = threadIdx.x;
    int lane = tid & 63, w = tid >> 6;

    __shared__ int lds_tot[128];
    __shared__ int lds_base[128];
    __shared__ int lds_sc;
    __shared__ int whist[512];                           // [4 waves][128 scores]
    if (tid < 128) lds_tot[tid] = tot[(b << 7) + tid];
    whist[tid] = 0;
    whist[tid + 256] = 0;

    int n = (chunk << 8) + tid;                          // anchor index within batch
    int packed = ms[(size_t)b * NPB + n];
    int s = packed >> 7;                                 // NEGV -> big negative
    __syncthreads();

    if (tid == 0) {                                      // redundant per-block cutoff (cheap)
        int cum = 0, sc = 1;
        for (int vv = 127; vv >= 1; vv--) {
            lds_base[vv] = cum;                          // count of items with score > vv
            cum += lds_tot[vv];
            sc = vv;
            if (cum >= KPRE) break;
        }
        lds_sc = sc;
    }
    if (s >= 1) atomicAdd(&whist[(w << 7) + s], 1);

    // intra-wave stable rank among equal scores (7 score bits; invalid lanes alias to
    // pattern 0 which never equals a valid s>=1)
    unsigned long long eq = ~0ull;
#pragma unroll
    for (int k = 0; k < 7; k++) {
        unsigned long long bk = __ballot((s >> k) & 1);
        eq &= ((s >> k) & 1) ? bk : ~bk;
    }
    int r = __popcll(eq & ((1ull << lane) - 1ull));
    __syncthreads();                                     // whist + lds_base/lds_sc ready

    int sc = lds_sc;
    if (s >= sc) {
        for (int w2 = 0; w2 < w; w2++) r += whist[(w2 << 7) + s];
        int pos = lds_base[s] + blockoff[((b << 7) + s) * NCHUNK + chunk] + r;
        if (pos < KPRE) {
            topv[(b << 12) + pos] = s;
            labk[(b << 12) + pos] = packed & 127;
            boxk[(b << 12) + pos] = boxes[(size_t)b * NPB + n];
        }
    }
}

// grid (64, 4, BATCH), 256 threads: masks for rows < R1 (4 row-chunks/block vs one
// column-chunk). Lower-triangle tiles write zeros AFTER the barrier. Diagonal tiles also
// emit a compact diag[b][row] word for the NMS wave's LDS staging.
__global__ __launch_bounds__(256) void dpp_mask_kernel(
        const float4* __restrict__ boxk, const int* __restrict__ labk,
        unsigned long long* __restrict__ mask, unsigned long long* __restrict__ diag) {
#pragma clang fp contract(off)
    int cc = blockIdx.x, rg = blockIdx.y, b = blockIdx.z;
    int t = threadIdx.x, lane = t & 63;
    int rc = (rg << 2) + (t >> 6);                       // 0..15
    int row = (rc << 6) + lane;                          // < R1
    __shared__ float4 cb[64];
    __shared__ int cl[64];
    int col0 = cc << 6;
    if (t < 64) {
        cb[t] = boxk[(b << 12) + col0 + t];
        cl[t] = labk[(b << 12) + col0 + t];
    }
    __syncthreads();
    size_t mi = ((size_t)b * R1 + row) * 64 + cc;
    if (cc < rc) {
        mask[mi] = 0ull;
        return;
    }
    float4 rbx = boxk[(b << 12) + row];
    int rl = labk[(b << 12) + row];
    float rw = fmaxf(rbx.z - rbx.x, 0.f), rh = fmaxf(rbx.w - rbx.y, 0.f);
    float ra = rw * rh;
    unsigned long long bits = 0ull;
#pragma unroll 4
    for (int j = 0; j < 64; j++) {
        bool sup = dpp_sup_test(rbx, ra, rl, cb[j], cl[j]) && ((col0 + j) > row);
        if (sup) bits |= (1ull << j);
    }
    mask[mi] = bits;
    if (cc == rc) diag[(size_t)b * R1 + row] = bits;     // row's own-chunk word
}

// grid (BATCH), 64 threads (one wave): greedy sequential pass, early exit at 300 kept.
// In-chunk dependency words come from LDS (staged diag); full row words (64-row slack)
// use a 24-deep (3x8 ring) global prefetch. Phase 2 = direct IoU fallback past R1.
__global__ __launch_bounds__(64) void dpp_nms_kernel(
        const float4* __restrict__ boxk, const int* __restrict__ labk, const int* __restrict__ topv,
        const unsigned long long* __restrict__ mask, const unsigned long long* __restrict__ diag,
        int* __restrict__ out) {
#pragma clang fp contract(off)
    int b = blockIdx.x, lane = threadIdx.x;
    const int* tv = topv + (b << 12);
    const unsigned long long* mrow = mask + (size_t)b * R1 * 64;

    __shared__ unsigned long long pu_lds[R1];            // 8 KB: diagonal words
    __shared__ int keep_lds[POSTK];
    for (int r2 = lane; r2 < R1; r2 += 64)               // coalesced stage
        pu_lds[r2] = diag[(size_t)b * R1 + r2];

    // lane l owns suppression word l (cols 64l..64l+63); pre-mark invalid (score==NEG)
    unsigned long long sup = 0ull;
    for (int k = 0; k < 64; k++) {
        int v = tv[(k << 6) + lane];
        unsigned long long mb = __ballot(v <= NEGV);
        if (lane == k) sup = mb;
    }
    __syncthreads();

    int kc = 0;
    unsigned long long w_win = __shfl(sup, 0);           // current-chunk window, wave-uniform

    unsigned long long pl[3][8];                         // 24-deep ring of full row words
#pragma unroll
    for (int g = 0; g < 3; g++)
#pragma unroll
        for (int u = 0; u < 8; u++)
            pl[g][u] = mrow[(size_t)(g * 8 + u) * 64 + lane];

    bool done = false;
    for (int ii = 0; ii < R1 && !done; ii += 8) {
        int g = (ii >> 3) % 3;
        unsigned long long pur[8];
#pragma unroll
        for (int u = 0; u < 8; u++) pur[u] = pu_lds[ii + u];
#pragma unroll
        for (int u = 0; u < 8; u++) {
            int i = ii + u;
            if (!done) {
                if ((i & 63) == 0 && i != 0) w_win = __shfl(sup, i >> 6);
                if (!((w_win >> (i & 63)) & 1ull)) {     // row i kept
                    if (lane == 0) keep_lds[kc] = i;
                    kc++;
                    if (kc == POSTK) {
                        done = true;
                    } else {
                        sup   |= pl[g][u];                // >=64-row slack before first read
                        w_win |= pur[u];                  // in-chunk, LDS-staged
                    }
                }
            }
            int r = ii + 24 + u;
            if (r > R1 - 1) r = R1 - 1;                   // clamp to stay in-bounds
            pl[g][u] = mrow[(size_t)r * 64 + lane];       // refill this ring slot
        }
    }

    // phase 2 (cold path, only if 300 keeps not reached within R1 rows)
    if (kc < POSTK) {
        for (int i = R1; i < KPRE && kc < POSTK; i++) {
            unsigned long long w = __shfl(sup, i >> 6);
            if ((w >> (i & 63)) & 1ull) continue;        // invalid/suppressed
            float4 bi = boxk[(b << 12) + i];
            int li = labk[(b << 12) + i];
            bool supp = false;
            for (int k = lane; k < kc; k += 64) {
                int j = keep_lds[k];
                float4 c = boxk[(b << 12) + j];
                float cw = fmaxf(c.z - c.x, 0.f), ch = fmaxf(c.w - c.y, 0.f);
                float ca = cw * ch;
                supp |= dpp_sup_test(c, ca, labk[(b << 12) + j], bi, li);
            }
            if (__ballot(supp)) {
                if (lane == (i >> 6)) sup |= 1ull << (i & 63);
            } else {
                if (lane == 0) keep_lds[kc] = i;
                kc++;
            }
        }
    }

    int kept = kc;
    if (kc < POSTK) {                                     // pad with suppressed/invalid slots in order
        for (int j = 0; j < KPRE && kc < POSTK; j++) {
            unsigned long long w = __shfl(sup, j >> 6);
            if ((w >> (j & 63)) & 1ull) {
                if (lane == 0) keep_lds[kc] = j;
                kc++;
            }
        }
    }
    __syncthreads();

    for (int k = lane; k < POSTK; k += 64) {
        int slot = keep_lds[k];
        float4 bx = boxk[(b << 12) + slot];
        int lb = labk[(b << 12) + slot];
        int sv = (k < kept) ? tv[slot] : NEGV;
        int o = ((b * POSTK) + k) << 2;
        out[o + 0] = (int)rintf(bx.x * 4.0f);            // round-half-even == jnp.round
        out[o + 1] = (int)rintf(bx.y * 4.0f);
        out[o + 2] = (int)rintf(bx.z * 4.0f);
        out[o + 3] = (int)rintf(bx.w * 4.0f);
        out[BATCH * POSTK * 4 + b * POSTK + k] = sv;
        out[BATCH * POSTK * 5 + b * POSTK + k] = lb;
    }
}

extern "C" void kernel_launch(void* const* d_in, const int* in_sizes, int n_in,
                              void* d_out, int out_size, void* d_ws, size_t ws_size,
                              hipStream_t stream) {
    const int*   data      = (const int*)d_in[0];
    const float* anchor    = (const float*)d_in[1];
    const int*   exp_table = (const int*)d_in[2];
    const int*   exp_shift = (const int*)d_in[3];

    char* ws = (char*)d_ws;
    float4* boxes  = (float4*)(ws + OFF_BOXES);
    int*    ms     = (int*)(ws + OFF_MS);
    int*    bcnt   = (int*)(ws + OFF_BCNT);
    int*    tot    = (int*)(ws + OFF_TOT);
    int*    topv   = (int*)(ws + OFF_TOPV);
    int*    labk   = (int*)(ws + OFF_LABK);
    float4* boxk   = (float4*)(ws + OFF_BOXK);
    unsigned long long* mask = (unsigned long long*)(ws + OFF_MASK);
    unsigned long long* diag = (unsigned long long*)(ws + OFF_DIAG);

    dpp_decode_kernel<<<dim3(16, NA, BATCH), 256, 0, stream>>>(
        data, anchor, exp_table, exp_shift, ms, boxes, bcnt);
    dpp_scan_kernel<<<dim3(128, BATCH), 384, 0, stream>>>(bcnt, tot, topv, labk, boxk);
    dpp_place_kernel<<<dim3(NCHUNK, BATCH), 256, 0, stream>>>(
        ms, boxes, bcnt, tot, topv, labk, boxk);
    dpp_mask_kernel<<<dim3(64, 4, BATCH), 256, 0, stream>>>(boxk, labk, mask, diag);
    dpp_nms_kernel<<<BATCH, 64, 0, stream>>>(boxk, labk, topv, mask, diag, (int*)d_out);
}

// Round 6
// 264.686 us; speedup vs baseline: 1.3759x; 1.3759x over previous
//
#include <hip/hip_runtime.h>
#include <stdint.h>

#define BATCH 4
#define NA 6
#define NC 80
#define HW (128*128)            // 16384
#define NPB (NA*HW)             // 98304 anchors per batch
#define KPRE 4095
#define POSTK 300
#define NEGV (-(1<<30))
#define NCHUNK (NPB/256)        // 384 chunks of 256 per batch
#define R1 1024                 // rows with precomputed NMS masks (fast path)

// ---------------- workspace layout (bytes) ----------------
#define OFF_BOXES    0                         // float4 [B][NPB]          6291456
#define OFF_MS       6291456                   // int [B][NPB] s<<7|lab    1572864
#define OFF_BCNT     7864320                   // int [B][128][384]         786432
#define OFF_TOT      8650752                   // int [B][128]                2048
#define OFF_TOPV     8652800                   // int [B][4096]              65536
#define OFF_LABK     8718336                   // int [B][4096]              65536
#define OFF_BOXK     8783872                   // float4 [B][4096]          262144
#define OFF_MASK     9046016                   // u64 [B][R1][64]          2097152
#define OFF_DIAG     11143168                  // u64 [B][R1]                32768
// total ~11.2 MB

__device__ __forceinline__ float4 dpp_decode_box(int dxi, int dyi, int dwi, int dhi,
                                                 float a0, float a1, float a2, float a3,
                                                 const int* __restrict__ exp_table, float esc) {
#pragma clang fp contract(off)
    float aw  = a2 - a0;
    float ah  = a3 - a1;
    float acx = (a0 + a2) * 0.5f;
    float acy = (a1 + a3) * 0.5f;
    float dx  = (float)dxi * 0.0625f;     // 1/2^INPUT_SHIFT
    float dy  = (float)dyi * 0.0625f;
    int e2 = dwi < -128 ? -128 : (dwi > 127 ? 127 : dwi);
    int e3 = dhi < -128 ? -128 : (dhi > 127 ? 127 : dhi);
    float ew = (float)exp_table[e2 + 128] * esc;
    float eh = (float)exp_table[e3 + 128] * esc;
    float pcx = acx + dx * aw;
    float pcy = acy + dy * ah;
    float pw = aw * ew;
    float ph = ah * eh;
    float x0 = pcx - pw * 0.5f;
    float y0 = pcy - ph * 0.5f;
    float x1 = pcx + pw * 0.5f;
    float y1 = pcy + ph * 0.5f;
    x0 = fminf(fmaxf(x0, 0.f), 1024.f);
    y0 = fminf(fmaxf(y0, 0.f), 1024.f);
    x1 = fminf(fmaxf(x1, 0.f), 1024.f);
    y1 = fminf(fmaxf(y1, 0.f), 1024.f);
    return make_float4(x0, y0, x1, y1);
}

// exact reference IoU-suppression test (fp contract off, IEEE divide)
__device__ __forceinline__ bool dpp_sup_test(float4 p, float pa, int pl_, float4 c, int cl_) {
#pragma clang fp contract(off)
    float cw = fmaxf(c.z - c.x, 0.f), ch = fmaxf(c.w - c.y, 0.f);
    float ca = cw * ch;
    float lx = fmaxf(p.x, c.x), ly = fmaxf(p.y, c.y);
    float rx = fminf(p.z, c.z), ry = fminf(p.w, c.w);
    float wx = fmaxf(rx - lx, 0.f), wy = fmaxf(ry - ly, 0.f);
    float inter = wx * wy;
    float uni = fmaxf((pa + ca) - inter, 1e-6f);
    float iou = inter / uni;
    return (iou > 0.5f) && (cl_ == pl_);
}

// grid (16, NA, BATCH), 256 threads; each thread decodes 4 anchors via int4 (16B/lane) loads.
// R3-proven structure; labels packed into ms as score<<7|label.
__global__ __launch_bounds__(256) void dpp_decode_kernel(
        const int* __restrict__ data, const float* __restrict__ anchor,
        const int* __restrict__ exp_table, const int* __restrict__ exp_shift_p,
        int* __restrict__ ms, float4* __restrict__ boxes, int* __restrict__ blockcnt) {
    int b = blockIdx.z, a = blockIdx.y, tid = threadIdx.x;
    int idx = blockIdx.x * 256 + tid;                    // int4 index in [0, 4096)
    const int4* dptr = (const int4*)(data + (size_t)(b * NA + a) * 84 * HW);

    int4 d0 = dptr[idx];
    int4 d1 = dptr[4096 + idx];
    int4 d2 = dptr[2 * 4096 + idx];
    int4 d3 = dptr[3 * 4096 + idx];

    int4 m = dptr[4 * 4096 + idx];
    int4 lab = make_int4(0, 0, 0, 0);
#pragma unroll 4
    for (int c = 1; c < NC; c++) {
        int4 v = dptr[(4 + c) * 4096 + idx];
        if (v.x > m.x) { m.x = v.x; lab.x = c; }         // strict > : first-argmax
        if (v.y > m.y) { m.y = v.y; lab.y = c; }
        if (v.z > m.z) { m.z = v.z; lab.z = c; }
        if (v.w > m.w) { m.w = v.w; lab.w = c; }
    }

    const float4* aptr = (const float4*)(anchor + (size_t)a * 4 * HW);
    float4 ax0 = aptr[idx];
    float4 ay0 = aptr[4096 + idx];
    float4 ax1 = aptr[2 * 4096 + idx];
    float4 ay1 = aptr[3 * 4096 + idx];

    int eshift = exp_shift_p[0];
    float esc = 1.0f / (float)(1 << eshift);

    float4 box0 = dpp_decode_box(d0.x, d1.x, d2.x, d3.x, ax0.x, ay0.x, ax1.x, ay1.x, exp_table, esc);
    float4 box1 = dpp_decode_box(d0.y, d1.y, d2.y, d3.y, ax0.y, ay0.y, ax1.y, ay1.y, exp_table, esc);
    float4 box2 = dpp_decode_box(d0.z, d1.z, d2.z, d3.z, ax0.z, ay0.z, ax1.z, ay1.z, exp_table, esc);
    float4 box3 = dpp_decode_box(d0.w, d1.w, d2.w, d3.w, ax0.w, ay0.w, ax1.w, ay1.w, exp_table, esc);

    int p0 = (m.x >= 1) ? ((m.x << 7) | lab.x) : NEGV;   // THR_INT = 1
    int p1 = (m.y >= 1) ? ((m.y << 7) | lab.y) : NEGV;
    int p2 = (m.z >= 1) ? ((m.z << 7) | lab.z) : NEGV;
    int p3 = (m.w >= 1) ? ((m.w << 7) | lab.w) : NEGV;

    size_t nb = (size_t)b * NPB + (size_t)a * HW;        // multiple of 4
    ((int4*)ms)[(nb >> 2) + idx] = make_int4(p0, p1, p2, p3);
    boxes[nb + 4 * (size_t)idx]     = box0;
    boxes[nb + 4 * (size_t)idx + 1] = box1;
    boxes[nb + 4 * (size_t)idx + 2] = box2;
    boxes[nb + 4 * (size_t)idx + 3] = box3;

    // per-256-anchor-chunk score histogram (stable counting-sort input)
    __shared__ int hist[512];                            // [4 quarters][128 scores]
    hist[tid] = 0;
    hist[tid + 256] = 0;
    __syncthreads();
    int q = tid >> 6;                                    // 64 threads * 4 anchors = 256-chunk
    if (m.x >= 1) atomicAdd(&hist[q * 128 + m.x], 1);
    if (m.y >= 1) atomicAdd(&hist[q * 128 + m.y], 1);
    if (m.z >= 1) atomicAdd(&hist[q * 128 + m.z], 1);
    if (m.w >= 1) atomicAdd(&hist[q * 128 + m.w], 1);
    __syncthreads();
#pragma unroll
    for (int k = 0; k < 2; k++) {
        int lin = tid + (k << 8);
        int q2 = lin >> 7, v = lin & 127;
        int chunk = a * 64 + blockIdx.x * 4 + q2;        // global 256-chunk id in [0,384)
        blockcnt[((b << 7) + v) * NCHUNK + chunk] = hist[q2 * 128 + v];
    }
}

// grid (128, BATCH), 384 threads: in-place exclusive scan of bcnt[b][v][0..384); total -> tot[b][v]
// (coalesced loads; shuffle scan). Also initializes this block's 32 slots of topv/labk/boxk.
__global__ __launch_bounds__(384) void dpp_scan_kernel(int* __restrict__ bcnt,
                                                       int* __restrict__ tot,
                                                       int* __restrict__ topv,
                                                       int* __restrict__ labk,
                                                       float4* __restrict__ boxk) {
    int v = blockIdx.x, b = blockIdx.y, t = threadIdx.x;
    if (t < 32) {
        int slot = (b << 12) + (v << 5) + t;
        topv[slot] = NEGV;
        labk[slot] = 0;
        boxk[slot] = make_float4(0.f, 0.f, 0.f, 0.f);
    }
    int* bc = bcnt + ((b << 7) + v) * NCHUNK;
    int x = bc[t];
    int lane = t & 63, w = t >> 6;                       // 6 waves
    int s = x;
#pragma unroll
    for (int d = 1; d < 64; d <<= 1) {
        int y = __shfl_up(s, d);
        if (lane >= d) s += y;
    }
    __shared__ int wsum[6];
    if (lane == 63) wsum[w] = s;
    __syncthreads();
    int off = 0;
    for (int i = 0; i < w; i++) off += wsum[i];
    int incl = s + off;
    bc[t] = incl - x;                                    // exclusive
    if (t == NCHUNK - 1) tot[(b << 7) + v] = incl;
}

// grid (NCHUNK, BATCH), 256 threads: fused cutoff (per-block redundant, from tot) + exact
// stable rank -> scatter into sorted topv/labk/boxk (box gathered from decode's output).
__global__ __launch_bounds__(256) void dpp_place_kernel(
        const int* __restrict__ ms, const float4* __restrict__ boxes,
        const int* __restrict__ blockoff, const int* __restrict__ tot,
        int* __restrict__ topv, int* __restrict__ labk, float4* __restrict__ boxk) {
    int chunk = blockIdx.x, b = blockIdx.y, tid = threadIdx.x;
    int lane = tid & 63, w = tid >> 6;

    __shared__ int lds_tot[128];
    __shared__ int lds_base[128];
    __shared__ int lds_sc;
    __shared__ int whist[512];                           // [4 waves][128 scores]
    if (tid < 128) lds_tot[tid] = tot[(b << 7) + tid];
    whist[tid] = 0;
    whist[tid + 256] = 0;

    int n = (chunk << 8) + tid;                          // anchor index within batch
    int packed = ms[(size_t)b * NPB + n];
    int s = packed >> 7;                                 // NEGV -> big negative
    __syncthreads();

    if (tid == 0) {                                      // redundant per-block cutoff (cheap)
        int cum = 0, sc = 1;
        for (int vv = 127; vv >= 1; vv--) {
            lds_base[vv] = cum;                          // count of items with score > vv
            cum += lds_tot[vv];
            sc = vv;
            if (cum >= KPRE) break;
        }
        lds_sc = sc;
    }
    if (s >= 1) atomicAdd(&whist[(w << 7) + s], 1);

    // intra-wave stable rank among equal scores (7 score bits; invalid lanes alias to
    // pattern 0 which never equals a valid s>=1)
    unsigned long long eq = ~0ull;
#pragma unroll
    for (int k = 0; k < 7; k++) {
        unsigned long long bk = __ballot((s >> k) & 1);
        eq &= ((s >> k) & 1) ? bk : ~bk;
    }
    int r = __popcll(eq & ((1ull << lane) - 1ull));
    __syncthreads();                                     // whist + lds_base/lds_sc ready

    int sc = lds_sc;
    if (s >= sc) {
        for (int w2 = 0; w2 < w; w2++) r += whist[(w2 << 7) + s];
        int pos = lds_base[s] + blockoff[((b << 7) + s) * NCHUNK + chunk] + r;
        if (pos < KPRE) {
            topv[(b << 12) + pos] = s;
            labk[(b << 12) + pos] = packed & 127;
            boxk[(b << 12) + pos] = boxes[(size_t)b * NPB + n];
        }
    }
}

// grid (64, 4, BATCH), 256 threads: masks for rows < R1 (4 row-chunks/block vs one
// column-chunk). Lower-triangle tiles write zeros AFTER the barrier. Diagonal tiles also
// emit a compact diag[b][row] word for the NMS wave's LDS staging.
__global__ __launch_bounds__(256) void dpp_mask_kernel(
        const float4* __restrict__ boxk, const int* __restrict__ labk,
        unsigned long long* __restrict__ mask, unsigned long long* __restrict__ diag) {
#pragma clang fp contract(off)
    int cc = blockIdx.x, rg = blockIdx.y, b = blockIdx.z;
    int t = threadIdx.x, lane = t & 63;
    int rc = (rg << 2) + (t >> 6);                       // 0..15
    int row = (rc << 6) + lane;                          // < R1
    __shared__ float4 cb[64];
    __shared__ int cl[64];
    int col0 = cc << 6;
    if (t < 64) {
        cb[t] = boxk[(b << 12) + col0 + t];
        cl[t] = labk[(b << 12) + col0 + t];
    }
    __syncthreads();
    size_t mi = ((size_t)b * R1 + row) * 64 + cc;
    if (cc < rc) {
        mask[mi] = 0ull;
        return;
    }
    float4 rbx = boxk[(b << 12) + row];
    int rl = labk[(b << 12) + row];
    float rw = fmaxf(rbx.z - rbx.x, 0.f), rh = fmaxf(rbx.w - rbx.y, 0.f);
    float ra = rw * rh;
    unsigned long long bits = 0ull;
#pragma unroll 4
    for (int j = 0; j < 64; j++) {
        bool sup = dpp_sup_test(rbx, ra, rl, cb[j], cl[j]) && ((col0 + j) > row);
        if (sup) bits |= (1ull << j);
    }
    mask[mi] = bits;
    if (cc == rc) diag[(size_t)b * R1 + row] = bits;     // row's own-chunk word
}

// grid (BATCH), 64 threads (one wave): greedy sequential pass, early exit at 300 kept.
// In-chunk dependency words from LDS-staged diag (register-prefetched 8/group); full row
// words via statically-indexed 8-deep prefetch (compile-time regs — NO dynamic indexing,
// that demotes the array to scratch: R5 post-mortem, 146 us). Phase 2 = direct IoU fallback.
__global__ __launch_bounds__(64) void dpp_nms_kernel(
        const float4* __restrict__ boxk, const int* __restrict__ labk, const int* __restrict__ topv,
        const unsigned long long* __restrict__ mask, const unsigned long long* __restrict__ diag,
        int* __restrict__ out) {
#pragma clang fp contract(off)
    int b = blockIdx.x, lane = threadIdx.x;
    const int* tv = topv + (b << 12);
    const unsigned long long* mrow = mask + (size_t)b * R1 * 64;

    __shared__ unsigned long long pu_lds[R1];            // 8 KB: diagonal words
    __shared__ int keep_lds[POSTK];
    for (int r2 = lane; r2 < R1; r2 += 64)               // coalesced stage
        pu_lds[r2] = diag[(size_t)b * R1 + r2];

    // lane l owns suppression word l (cols 64l..64l+63); pre-mark invalid (score==NEG)
    unsigned long long sup = 0ull;
    for (int k = 0; k < 64; k++) {
        int v = tv[(k << 6) + lane];
        unsigned long long mb = __ballot(v <= NEGV);
        if (lane == k) sup = mb;
    }
    __syncthreads();

    int kc = 0;
    unsigned long long w_win = __shfl(sup, 0);           // current-chunk window, wave-uniform

    unsigned long long pl[8];                            // 8-deep, statically indexed
#pragma unroll
    for (int u = 0; u < 8; u++)
        pl[u] = mrow[(size_t)u * 64 + lane];

    bool done = false;
    for (int ii = 0; ii < R1 && !done; ii += 8) {
        unsigned long long pur[8];
#pragma unroll
        for (int u = 0; u < 8; u++) pur[u] = pu_lds[ii + u];
#pragma unroll
        for (int u = 0; u < 8; u++) {
            int i = ii + u;
            if (!done) {
                if ((i & 63) == 0 && i != 0) w_win = __shfl(sup, i >> 6);
                if (!((w_win >> (i & 63)) & 1ull)) {     // row i kept
                    if (lane == 0) keep_lds[kc] = i;
                    kc++;
                    if (kc == POSTK) {
                        done = true;
                    } else {
                        sup   |= pl[u];                   // off critical chain (64-iter slack)
                        w_win |= pur[u];                  // in-chunk, LDS-staged
                    }
                }
            }
            int r = i + 8;
            if (r > R1 - 1) r = R1 - 1;                   // clamp to stay in-bounds
            pl[u] = mrow[(size_t)r * 64 + lane];          // refill (static index u)
        }
    }

    // phase 2 (cold path, only if 300 keeps not reached within R1 rows)
    if (kc < POSTK) {
        for (int i = R1; i < KPRE && kc < POSTK; i++) {
            unsigned long long w = __shfl(sup, i >> 6);
            if ((w >> (i & 63)) & 1ull) continue;        // invalid/suppressed
            float4 bi = boxk[(b << 12) + i];
            int li = labk[(b << 12) + i];
            bool supp = false;
            for (int k = lane; k < kc; k += 64) {
                int j = keep_lds[k];
                float4 c = boxk[(b << 12) + j];
                float cw = fmaxf(c.z - c.x, 0.f), ch = fmaxf(c.w - c.y, 0.f);
                float ca = cw * ch;
                supp |= dpp_sup_test(c, ca, labk[(b << 12) + j], bi, li);
            }
            if (__ballot(supp)) {
                if (lane == (i >> 6)) sup |= 1ull << (i & 63);
            } else {
                if (lane == 0) keep_lds[kc] = i;
                kc++;
            }
        }
    }

    int kept = kc;
    if (kc < POSTK) {                                     // pad with suppressed/invalid slots in order
        for (int j = 0; j < KPRE && kc < POSTK; j++) {
            unsigned long long w = __shfl(sup, j >> 6);
            if ((w >> (j & 63)) & 1ull) {
                if (lane == 0) keep_lds[kc] = j;
                kc++;
            }
        }
    }
    __syncthreads();

    for (int k = lane; k < POSTK; k += 64) {
        int slot = keep_lds[k];
        float4 bx = boxk[(b << 12) + slot];
        int lb = labk[(b << 12) + slot];
        int sv = (k < kept) ? tv[slot] : NEGV;
        int o = ((b * POSTK) + k) << 2;
        out[o + 0] = (int)rintf(bx.x * 4.0f);            // round-half-even == jnp.round
        out[o + 1] = (int)rintf(bx.y * 4.0f);
        out[o + 2] = (int)rintf(bx.z * 4.0f);
        out[o + 3] = (int)rintf(bx.w * 4.0f);
        out[BATCH * POSTK * 4 + b * POSTK + k] = sv;
        out[BATCH * POSTK * 5 + b * POSTK + k] = lb;
    }
}

extern "C" void kernel_launch(void* const* d_in, const int* in_sizes, int n_in,
                              void* d_out, int out_size, void* d_ws, size_t ws_size,
                              hipStream_t stream) {
    const int*   data      = (const int*)d_in[0];
    const float* anchor    = (const float*)d_in[1];
    const int*   exp_table = (const int*)d_in[2];
    const int*   exp_shift = (const int*)d_in[3];

    char* ws = (char*)d_ws;
    float4* boxes  = (float4*)(ws + OFF_BOXES);
    int*    ms     = (int*)(ws + OFF_MS);
    int*    bcnt   = (int*)(ws + OFF_BCNT);
    int*    tot    = (int*)(ws + OFF_TOT);
    int*    topv   = (int*)(ws + OFF_TOPV);
    int*    labk   = (int*)(ws + OFF_LABK);
    float4* boxk   = (float4*)(ws + OFF_BOXK);
    unsigned long long* mask = (unsigned long long*)(ws + OFF_MASK);
    unsigned long long* diag = (unsigned long long*)(ws + OFF_DIAG);

    dpp_decode_kernel<<<dim3(16, NA, BATCH), 256, 0, stream>>>(
        data, anchor, exp_table, exp_shift, ms, boxes, bcnt);
    dpp_scan_kernel<<<dim3(128, BATCH), 384, 0, stream>>>(bcnt, tot, topv, labk, boxk);
    dpp_place_kernel<<<dim3(NCHUNK, BATCH), 256, 0, stream>>>(
        ms, boxes, bcnt, tot, topv, labk, boxk);
    dpp_mask_kernel<<<dim3(64, 4, BATCH), 256, 0, stream>>>(boxk, labk, mask, diag);
    dpp_nms_kernel<<<BATCH, 64, 0, stream>>>(boxk, labk, topv, mask, diag, (int*)d_out);
}